// Round 12
// baseline (315.753 us; speedup 1.0000x reference)
//
#include <hip/hip_runtime.h>
#include <cstdint>
#include <cstddef>

typedef unsigned short u16;
typedef __attribute__((ext_vector_type(8))) short bf16x8;
typedef __attribute__((ext_vector_type(4))) float f32x4;

__device__ inline float bl(uint32_t u){ union{float f;uint32_t i;}c; c.i = u<<16; return c.f; }
__device__ inline float bh(uint32_t u){ union{float f;uint32_t i;}c; c.i = u & 0xFFFF0000u; return c.f; }
__device__ inline u16 f2bu(float f){
  union{float f;uint32_t u;} c; c.f=f;
  uint32_t u=c.u;
  return (u16)((u + 0x7FFFu + ((u>>16)&1u))>>16);  // RNE
}

#define GLOAD_LDS16(g, l) __builtin_amdgcn_global_load_lds( \
    (__attribute__((address_space(1))) void*)(g), \
    (__attribute__((address_space(3))) void*)(l), 16, 0, 0)
#define BAR() do{ asm volatile("" ::: "memory"); __builtin_amdgcn_s_barrier(); asm volatile("" ::: "memory"); }while(0)

// ---------------- fused convert: X f32->bf16 (blocks 0..2047) + W transpose (blocks 2048..5119) --
__global__ __launch_bounds__(256) void k_conv(const float* __restrict__ X,
                                              u16* __restrict__ Xb,
                                              const float* __restrict__ W,
                                              u16* __restrict__ Wt){
  __shared__ float t[32][33];
  int b = blockIdx.x;
  if (b < 2048){
    int i = b*256 + threadIdx.x;
    for (; i < 4194304; i += 2048*256){
      float4 v = ((const float4*)X)[i];
      ushort4 o;
      o.x=f2bu(v.x); o.y=f2bu(v.y); o.z=f2bu(v.z); o.w=f2bu(v.w);
      ((ushort4*)Xb)[i] = o;
    }
  } else {
    int bb = b - 2048;                 // 0..3071
    int n0 = (bb % 96)*32, k0 = (bb / 96)*32;
    int tx = threadIdx.x & 31, ty = threadIdx.x >> 5;
    #pragma unroll
    for (int i=0;i<32;i+=8)
      t[ty+i][tx] = W[(size_t)(k0+ty+i)*3072 + n0+tx];
    __syncthreads();
    #pragma unroll
    for (int i=0;i<32;i+=8)
      Wt[(size_t)(n0+ty+i)*1024 + k0+tx] = f2bu(t[tx][ty+i]);
  }
}

// ---------------- GEMM: Qkv[16384][3072] = Xb[M][K]*Wt[N][K]^T + bias, bf16 out ----------------
// r11 dataflow (verified) with 4 WAVES x 128x128-per-wave (LDS frag-read traffic 96->64KB/tile,
// lifting the LDS-BW ceiling 62%->83%). 5 buffers (160KB), one barrier per 2 K-tiles, counted
// vmcnt (8 loads/wave/tile now), same XOR swizzle (0-conflict, r9-r11), LDS-staged epilogue.
__global__ __launch_bounds__(256, 1) void k_gemm2(const u16* __restrict__ Xb,
                                                  const u16* __restrict__ Wt,
                                                  const float* __restrict__ bias,
                                                  u16* __restrict__ Q){
  __shared__ __align__(16) u16 L[81920];   // 5 bufs x [A0,A1,B0,B1][4096 u16] = 160 KiB
  const int K = 1024, N = 3072, NT = 32;
  int b = blockIdx.x;
  // XCD swizzle: nwg=768, 768%8==0 -> bijective
  int swz = (b & 7)*96 + (b >> 3);
  int bm = swz / 12, bn = swz % 12;
  int m0 = bm*256, n0 = bn*256;
  int tid = threadIdx.x, w = tid>>6, lane = tid&63, lr = lane&15, lk = lane>>4;
  int wm = w>>1, wn = w&1;

  f32x4 acc[8][8];
  #pragma unroll
  for (int i=0;i<8;i++)
    #pragma unroll
    for (int j=0;j<8;j++)
      acc[i][j] = (f32x4){0.f,0.f,0.f,0.f};

  // ---- staging source (inverse-swizzled, r8-r11 verified pattern; 256 threads -> 2 half-calls
  // per 8KB sub-buffer, rows tid>>2 + {0,64})
  int grow = tid>>2;
  int gcol = ((((tid&3)*16) ^ (((tid>>3)&1)<<4) ^ (((tid>>4)&1)<<5)) >> 1);
  const u16* gA = Xb + (size_t)(m0 + grow)*K + gcol;   // +64/128/192 rows via *K offsets
  const u16* gB = Wt + (size_t)(n0 + grow)*K + gcol;
  const size_t r64 = (size_t)64*K;

#define STG(j) do{ int bf=(j)%5, kof=(j)*32; \
    GLOAD_LDS16(gA + kof,          &L[((bf*4+0)<<12) + tid*8]); \
    GLOAD_LDS16(gA + r64 + kof,    &L[((bf*4+0)<<12) + 2048 + tid*8]); \
    GLOAD_LDS16(gA + 2*r64 + kof,  &L[((bf*4+1)<<12) + tid*8]); \
    GLOAD_LDS16(gA + 3*r64 + kof,  &L[((bf*4+1)<<12) + 2048 + tid*8]); \
    GLOAD_LDS16(gB + kof,          &L[((bf*4+2)<<12) + tid*8]); \
    GLOAD_LDS16(gB + r64 + kof,    &L[((bf*4+2)<<12) + 2048 + tid*8]); \
    GLOAD_LDS16(gB + 2*r64 + kof,  &L[((bf*4+3)<<12) + tid*8]); \
    GLOAD_LDS16(gB + 3*r64 + kof,  &L[((bf*4+3)<<12) + 2048 + tid*8]); }while(0)

  // ---- read-side swizzled addressing (identical sub-buffer layout to r8-r11)
  const char* Lb = (const char*)L;
  int colx = (lk*16) ^ (((lr>>1)&3)*16);
  int frow = lr*64 + colx;                 // + mi*1024 / + ni*1024

#define TILE_BODY(bufidx) do{ \
    int Abase = ((bufidx)*4 + wm) << 13; \
    int Bbase = ((bufidx)*4 + 2 + wn) << 13; \
    bf16x8 af[8], bfr[8]; \
    _Pragma("unroll") \
    for (int i=0;i<8;i++) af[i]  = *(const bf16x8*)(Lb + Abase + i*1024 + frow); \
    _Pragma("unroll") \
    for (int i=0;i<8;i++) bfr[i] = *(const bf16x8*)(Lb + Bbase + i*1024 + frow); \
    __builtin_amdgcn_s_setprio(1); \
    _Pragma("unroll") \
    for (int mi=0;mi<8;mi++) \
      _Pragma("unroll") \
      for (int ni=0;ni<8;ni++) \
        acc[mi][ni] = __builtin_amdgcn_mfma_f32_16x16x32_bf16(af[mi], bfr[ni], acc[mi][ni], 0,0,0); \
    __builtin_amdgcn_s_setprio(0); }while(0)

  // prologue: stage tiles 0,1,2 (24 loads/wave); vmcnt(8) -> tiles 0,1 landed (STG(2) in flight)
  STG(0); STG(1); STG(2);
  asm volatile("s_waitcnt vmcnt(8)" ::: "memory");
  __builtin_amdgcn_sched_barrier(0);
  BAR();

  for (int t = 0; t < NT; t += 2){
    if (t+3 < NT) STG(t+3);
    TILE_BODY(t%5);
    if (t+4 < NT) STG(t+4);
    TILE_BODY((t+1)%5);
    asm volatile("s_waitcnt lgkmcnt(0)" ::: "memory");
    if      (t+4 < NT) { asm volatile("s_waitcnt vmcnt(8)" ::: "memory"); }
    else if (t+2 < NT) { asm volatile("s_waitcnt vmcnt(0)" ::: "memory"); }
    __builtin_amdgcn_sched_barrier(0);
    BAR();
  }
#undef STG
#undef TILE_BODY

  // ---- epilogue: per-wave 128x128 C region in LDS (32KB, swizzled), then 32 coalesced passes
  {
    u16* reg = &L[w*16384];
    #pragma unroll
    for (int ni=0; ni<8; ++ni){
      int col = ni*16 + lr;
      float bv = bias[n0 + wn*128 + col];
      #pragma unroll
      for (int mi=0; mi<8; ++mi){
        #pragma unroll
        for (int r=0;r<4;r++){
          int rr = mi*16 + lk*4 + r;
          reg[rr*128 + (col ^ ((rr&15)<<3))] = f2bu(acc[mi][ni][r] + bv);
        }
      }
    }
    asm volatile("s_waitcnt lgkmcnt(0)" ::: "memory");
    BAR();
    int co = (tid&31)*8;                 // col 0..255 step 8
    #pragma unroll
    for (int p=0; p<32; ++p){
      int rI = p*8 + (tid>>5);
      int wreg = ((rI>>7)<<1) + (co>>7);
      int rr = rI & 127;
      int cc = co & 127;
      const u16* src = &L[wreg*16384 + rr*128 + (cc ^ ((rr&15)<<3))];
      uint4 v = *(const uint4*)src;
      *(uint4*)&Q[(size_t)(m0+rI)*N + n0 + co] = v;
    }
  }
}

// ---------------- per-token head-attention (bf16 qkv input; r4/r7/r9 verified) ----------------
__device__ inline void load16fb(const u16* p, float* f){
  uint4 a = ((const uint4*)p)[0], b4 = ((const uint4*)p)[1];
  f[0]=bl(a.x);  f[1]=bh(a.x);  f[2]=bl(a.y);  f[3]=bh(a.y);
  f[4]=bl(a.z);  f[5]=bh(a.z);  f[6]=bl(a.w);  f[7]=bh(a.w);
  f[8]=bl(b4.x); f[9]=bh(b4.x); f[10]=bl(b4.y);f[11]=bh(b4.y);
  f[12]=bl(b4.z);f[13]=bh(b4.z);f[14]=bl(b4.w);f[15]=bh(b4.w);
}

// 1 wave per token; lane = h*4 + dq; dq owns d in [dq*16, dq*16+16).
__global__ __launch_bounds__(256) void k_attn(const u16* __restrict__ Qkv,
                                              float* __restrict__ out){
  __shared__ __align__(16) u16 sm[4][3072];
  int w = threadIdx.x>>6, lane = threadIdx.x&63;
  int token = blockIdx.x*4 + w;
  const uint4* src = (const uint4*)(Qkv + (size_t)token*3072);
  uint4* dst = (uint4*)&sm[w][0];
  for (int i = lane; i < 384; i += 64) dst[i] = src[i];
  __syncthreads();

  int h = lane>>2, dq = lane&3;
  const u16* base = &sm[w][0];
  float qf[16];
  load16fb(base + h*192 + dq*16, qf);

  const float scale = 0.07216878364870323f;  // 1/sqrt(192)
  float s[16];
  #pragma unroll
  for (int g=0; g<16; ++g){
    float kf[16];
    load16fb(base + g*192 + 64 + dq*16, kf);
    float a = 0.f;
    #pragma unroll
    for (int j=0;j<16;j++) a += qf[j]*kf[j];
    a += __shfl_xor(a, 1);
    a += __shfl_xor(a, 2);
    s[g] = a * scale;
  }
  float mx = s[0];
  #pragma unroll
  for (int g=1; g<16; ++g) mx = fmaxf(mx, s[g]);
  float sum = 0.f;
  #pragma unroll
  for (int g=0; g<16; ++g){ s[g] = __expf(s[g]-mx); sum += s[g]; }
  float inv = 1.f/sum;

  float o[16];
  #pragma unroll
  for (int j=0;j<16;j++) o[j] = 0.f;
  #pragma unroll
  for (int g=0; g<16; ++g){
    float wg = s[g]*inv;
    float vf[16];
    load16fb(base + g*192 + 128 + dq*16, vf);
    #pragma unroll
    for (int j=0;j<16;j++) o[j] += wg*vf[j];
  }
  float* op = out + (size_t)token*1024 + h*64 + dq*16;
  #pragma unroll
  for (int i=0;i<4;i++)
    ((float4*)op)[i] = make_float4(o[i*4], o[i*4+1], o[i*4+2], o[i*4+3]);
}

// ---------------- fallback (ws too small): fully fused, f32 VALU, slow but correct ----------------
__global__ __launch_bounds__(256) void k_fallback(const float* __restrict__ X,
                                                  const float* __restrict__ W,
                                                  const float* __restrict__ bias,
                                                  float* __restrict__ out){
  int token = blockIdx.x;
  __shared__ float xs[1024];
  __shared__ float qkvs[3072];
  __shared__ float ss[16][16];
  __shared__ float ww[16][16];
  for (int i=threadIdx.x; i<1024; i+=256) xs[i] = X[(size_t)token*1024 + i];
  __syncthreads();
  for (int n=threadIdx.x; n<3072; n+=256){
    float acc = bias[n];
    for (int k=0;k<1024;k++) acc += xs[k]*W[(size_t)k*3072 + n];
    qkvs[n] = acc;
  }
  __syncthreads();
  {
    int t = threadIdx.x, h = t>>4, g = t&15;
    float a = 0.f;
    for (int d=0; d<64; d++) a += qkvs[h*192 + d]*qkvs[g*192 + 64 + d];
    ss[h][g] = a * 0.07216878364870323f;
  }
  __syncthreads();
  if (threadIdx.x < 16){
    int hh = threadIdx.x;
    float m = -1e30f;
    for (int g=0;g<16;g++) m = fmaxf(m, ss[hh][g]);
    float sum = 0.f;
    for (int g=0;g<16;g++){ float e = __expf(ss[hh][g]-m); ww[hh][g]=e; sum+=e; }
    float inv = 1.f/sum;
    for (int g=0;g<16;g++) ww[hh][g] *= inv;
  }
  __syncthreads();
  for (int i=threadIdx.x; i<1024; i+=256){
    int h = i>>6, d = i&63;
    float a = 0.f;
    for (int g=0;g<16;g++) a += ww[h][g]*qkvs[g*192 + 128 + d];
    out[(size_t)token*1024 + i] = a;
  }
}

extern "C" void kernel_launch(void* const* d_in, const int* in_sizes, int n_in,
                              void* d_out, int out_size, void* d_ws, size_t ws_size,
                              hipStream_t stream){
  const float* x    = (const float*)d_in[0];   // [4,4096,1024] f32
  const float* wk   = (const float*)d_in[1];   // [1024,16,192] f32
  const float* bias = (const float*)d_in[2];   // [16,192] f32
  float* out = (float*)d_out;                  // [4,4096,16,64] f32

  const size_t offW = 33554432;                       // Xb: 16M bf16
  const size_t offQ = offW + 6291456;                 // Wt: 3M bf16
  const size_t need = offQ + (size_t)16384*3072*2;    // Q bf16

  if (ws_size >= need){
    u16* Xb = (u16*)d_ws;
    u16* Wt = (u16*)((char*)d_ws + offW);
    u16* Q  = (u16*)((char*)d_ws + offQ);
    k_conv  <<<5120, 256, 0, stream>>>(x, Xb, wk, Wt);
    k_gemm2 <<<768, 256, 0, stream>>>(Xb, Wt, bias, Q);
    k_attn  <<<4096, 256, 0, stream>>>(Q, out);
  } else {
    k_fallback<<<16384, 256, 0, stream>>>(x, wk, bias, out);
  }
}

// Round 13
// 190.283 us; speedup vs baseline: 1.6594x; 1.6594x over previous
//
#include <hip/hip_runtime.h>
#include <cstdint>
#include <cstddef>

typedef unsigned short u16;
typedef __attribute__((ext_vector_type(8))) short bf16x8;
typedef __attribute__((ext_vector_type(4))) float f32x4;

__device__ inline float bl(uint32_t u){ union{float f;uint32_t i;}c; c.i = u<<16; return c.f; }
__device__ inline float bh(uint32_t u){ union{float f;uint32_t i;}c; c.i = u & 0xFFFF0000u; return c.f; }
__device__ inline u16 f2bu(float f){
  union{float f;uint32_t u;} c; c.f=f;
  uint32_t u=c.u;
  return (u16)((u + 0x7FFFu + ((u>>16)&1u))>>16);  // RNE
}

#define GLOAD_LDS16(g, l) __builtin_amdgcn_global_load_lds( \
    (__attribute__((address_space(1))) void*)(g), \
    (__attribute__((address_space(3))) void*)(l), 16, 0, 0)
#define BAR() do{ asm volatile("" ::: "memory"); __builtin_amdgcn_s_barrier(); asm volatile("" ::: "memory"); }while(0)
#define WAITVM(n) do{ asm volatile("s_waitcnt vmcnt(" #n ")" ::: "memory"); __builtin_amdgcn_sched_barrier(0); }while(0)

// ---------------- fused convert: X f32->bf16 (blocks 0..2047) + W transpose (blocks 2048..5119) --
__global__ __launch_bounds__(256) void k_conv(const float* __restrict__ X,
                                              u16* __restrict__ Xb,
                                              const float* __restrict__ W,
                                              u16* __restrict__ Wt){
  __shared__ float t[32][33];
  int b = blockIdx.x;
  if (b < 2048){
    int i = b*256 + threadIdx.x;
    for (; i < 4194304; i += 2048*256){
      float4 v = ((const float4*)X)[i];
      ushort4 o;
      o.x=f2bu(v.x); o.y=f2bu(v.y); o.z=f2bu(v.z); o.w=f2bu(v.w);
      ((ushort4*)Xb)[i] = o;
    }
  } else {
    int bb = b - 2048;                 // 0..3071
    int n0 = (bb % 96)*32, k0 = (bb / 96)*32;
    int tx = threadIdx.x & 31, ty = threadIdx.x >> 5;
    #pragma unroll
    for (int i=0;i<32;i+=8)
      t[ty+i][tx] = W[(size_t)(k0+ty+i)*3072 + n0+tx];
    __syncthreads();
    #pragma unroll
    for (int i=0;i<32;i+=8)
      Wt[(size_t)(n0+ty+i)*1024 + k0+tx] = f2bu(t[tx][ty+i]);
  }
}

// ---------------- GEMM: Qkv[16384][3072] = Xb[M][K]*Wt[N][K]^T + bias, bf16 out ----------------
// r11 structure (verified 107us): 256x256 tile, BK=32, 8 waves, 5 LDS buffers (160KB), one
// barrier per 2 K-tiles, XOR-swizzled LDS (0 conflicts), LDS-staged epilogue (WRITE=96MB).
// r13 change: vmcnt gate MOVED to just before each TILE_BODY, counting only the tile about to
// be read (distance-3 prefetch now actually hides HBM latency; r11 gated at window end on a
// same-window stage -> ~300cyc/window guaranteed stall). Hazard analysis unchanged from r11.
__global__ __launch_bounds__(512, 1) void k_gemm2(const u16* __restrict__ Xb,
                                                  const u16* __restrict__ Wt,
                                                  const float* __restrict__ bias,
                                                  u16* __restrict__ Q){
  __shared__ __align__(16) u16 L[81920];   // 5 bufs x [A0,A1,B0,B1][4096 u16] = 160 KiB
  const int K = 1024, N = 3072, NT = 32;
  int b = blockIdx.x;
  // XCD swizzle: nwg=768, 768%8==0 -> bijective
  int swz = (b & 7)*96 + (b >> 3);
  int bm = swz / 12, bn = swz % 12;
  int m0 = bm*256, n0 = bn*256;
  int tid = threadIdx.x, w = tid>>6, lane = tid&63, lr = lane&15, lk = lane>>4;
  int wm = w>>2, wn = w&3;

  f32x4 acc[8][4];
  #pragma unroll
  for (int i=0;i<8;i++)
    #pragma unroll
    for (int j=0;j<4;j++)
      acc[i][j] = (f32x4){0.f,0.f,0.f,0.f};

  // ---- staging source (inverse-swizzled, r8-r11 verified)
  int grow = tid>>2;
  int gcol = ((((tid&3)*16) ^ (((tid>>3)&1)<<4) ^ (((tid>>4)&1)<<5)) >> 1);
  const u16* gA0 = Xb + (size_t)(m0 + grow)*K + gcol;
  const u16* gA1 = Xb + (size_t)(m0 + 128 + grow)*K + gcol;
  const u16* gB0 = Wt + (size_t)(n0 + grow)*K + gcol;
  const u16* gB1 = Wt + (size_t)(n0 + 128 + grow)*K + gcol;

#define STG(j) do{ int bf=(j)%5, kof=(j)*32; \
    GLOAD_LDS16(gA0+kof, &L[((bf*4+0)<<12) + tid*8]); \
    GLOAD_LDS16(gA1+kof, &L[((bf*4+1)<<12) + tid*8]); \
    GLOAD_LDS16(gB0+kof, &L[((bf*4+2)<<12) + tid*8]); \
    GLOAD_LDS16(gB1+kof, &L[((bf*4+3)<<12) + tid*8]); }while(0)

  // ---- read-side swizzled addressing (r8-r11 verified)
  const char* Lb = (const char*)L;
  int colx = (lk*16) ^ (((lr>>1)&3)*16);
  int arow = lr*64 + colx;
  int brow = ((wn&1)*64 + lr)*64 + colx;

#define TILE_BODY(bufidx) do{ \
    int Abase = ((bufidx)*4 + wm) << 13; \
    int Bbase = ((bufidx)*4 + 2 + (wn>>1)) << 13; \
    bf16x8 a0,a1,a2,a3,a4,a5,a6,a7, b0,b1,b2,b3; \
    a0 = *(const bf16x8*)(Lb + Abase + 0*1024 + arow); \
    a1 = *(const bf16x8*)(Lb + Abase + 1*1024 + arow); \
    a2 = *(const bf16x8*)(Lb + Abase + 2*1024 + arow); \
    a3 = *(const bf16x8*)(Lb + Abase + 3*1024 + arow); \
    a4 = *(const bf16x8*)(Lb + Abase + 4*1024 + arow); \
    a5 = *(const bf16x8*)(Lb + Abase + 5*1024 + arow); \
    a6 = *(const bf16x8*)(Lb + Abase + 6*1024 + arow); \
    a7 = *(const bf16x8*)(Lb + Abase + 7*1024 + arow); \
    b0 = *(const bf16x8*)(Lb + Bbase + 0*1024 + brow); \
    b1 = *(const bf16x8*)(Lb + Bbase + 1*1024 + brow); \
    b2 = *(const bf16x8*)(Lb + Bbase + 2*1024 + brow); \
    b3 = *(const bf16x8*)(Lb + Bbase + 3*1024 + brow); \
    __builtin_amdgcn_s_setprio(1); \
    acc[0][0] = __builtin_amdgcn_mfma_f32_16x16x32_bf16(a0, b0, acc[0][0], 0,0,0); \
    acc[0][1] = __builtin_amdgcn_mfma_f32_16x16x32_bf16(a0, b1, acc[0][1], 0,0,0); \
    acc[0][2] = __builtin_amdgcn_mfma_f32_16x16x32_bf16(a0, b2, acc[0][2], 0,0,0); \
    acc[0][3] = __builtin_amdgcn_mfma_f32_16x16x32_bf16(a0, b3, acc[0][3], 0,0,0); \
    acc[1][0] = __builtin_amdgcn_mfma_f32_16x16x32_bf16(a1, b0, acc[1][0], 0,0,0); \
    acc[1][1] = __builtin_amdgcn_mfma_f32_16x16x32_bf16(a1, b1, acc[1][1], 0,0,0); \
    acc[1][2] = __builtin_amdgcn_mfma_f32_16x16x32_bf16(a1, b2, acc[1][2], 0,0,0); \
    acc[1][3] = __builtin_amdgcn_mfma_f32_16x16x32_bf16(a1, b3, acc[1][3], 0,0,0); \
    acc[2][0] = __builtin_amdgcn_mfma_f32_16x16x32_bf16(a2, b0, acc[2][0], 0,0,0); \
    acc[2][1] = __builtin_amdgcn_mfma_f32_16x16x32_bf16(a2, b1, acc[2][1], 0,0,0); \
    acc[2][2] = __builtin_amdgcn_mfma_f32_16x16x32_bf16(a2, b2, acc[2][2], 0,0,0); \
    acc[2][3] = __builtin_amdgcn_mfma_f32_16x16x32_bf16(a2, b3, acc[2][3], 0,0,0); \
    acc[3][0] = __builtin_amdgcn_mfma_f32_16x16x32_bf16(a3, b0, acc[3][0], 0,0,0); \
    acc[3][1] = __builtin_amdgcn_mfma_f32_16x16x32_bf16(a3, b1, acc[3][1], 0,0,0); \
    acc[3][2] = __builtin_amdgcn_mfma_f32_16x16x32_bf16(a3, b2, acc[3][2], 0,0,0); \
    acc[3][3] = __builtin_amdgcn_mfma_f32_16x16x32_bf16(a3, b3, acc[3][3], 0,0,0); \
    acc[4][0] = __builtin_amdgcn_mfma_f32_16x16x32_bf16(a4, b0, acc[4][0], 0,0,0); \
    acc[4][1] = __builtin_amdgcn_mfma_f32_16x16x32_bf16(a4, b1, acc[4][1], 0,0,0); \
    acc[4][2] = __builtin_amdgcn_mfma_f32_16x16x32_bf16(a4, b2, acc[4][2], 0,0,0); \
    acc[4][3] = __builtin_amdgcn_mfma_f32_16x16x32_bf16(a4, b3, acc[4][3], 0,0,0); \
    acc[5][0] = __builtin_amdgcn_mfma_f32_16x16x32_bf16(a5, b0, acc[5][0], 0,0,0); \
    acc[5][1] = __builtin_amdgcn_mfma_f32_16x16x32_bf16(a5, b1, acc[5][1], 0,0,0); \
    acc[5][2] = __builtin_amdgcn_mfma_f32_16x16x32_bf16(a5, b2, acc[5][2], 0,0,0); \
    acc[5][3] = __builtin_amdgcn_mfma_f32_16x16x32_bf16(a5, b3, acc[5][3], 0,0,0); \
    acc[6][0] = __builtin_amdgcn_mfma_f32_16x16x32_bf16(a6, b0, acc[6][0], 0,0,0); \
    acc[6][1] = __builtin_amdgcn_mfma_f32_16x16x32_bf16(a6, b1, acc[6][1], 0,0,0); \
    acc[6][2] = __builtin_amdgcn_mfma_f32_16x16x32_bf16(a6, b2, acc[6][2], 0,0,0); \
    acc[6][3] = __builtin_amdgcn_mfma_f32_16x16x32_bf16(a6, b3, acc[6][3], 0,0,0); \
    acc[7][0] = __builtin_amdgcn_mfma_f32_16x16x32_bf16(a7, b0, acc[7][0], 0,0,0); \
    acc[7][1] = __builtin_amdgcn_mfma_f32_16x16x32_bf16(a7, b1, acc[7][1], 0,0,0); \
    acc[7][2] = __builtin_amdgcn_mfma_f32_16x16x32_bf16(a7, b2, acc[7][2], 0,0,0); \
    acc[7][3] = __builtin_amdgcn_mfma_f32_16x16x32_bf16(a7, b3, acc[7][3], 0,0,0); \
    __builtin_amdgcn_s_setprio(0); }while(0)

  // prologue: stage tiles 0,1,2 (12 loads/thread in flight)
  STG(0); STG(1); STG(2);
  BAR();

  for (int t = 0; t < NT; t += 2){
    if (t+3 < NT) STG(t+3);
    // gate: tile t complete. outstanding tiles ⊆ {t..t+3} (16 loads) -> vmcnt(12);
    // tail t=30: ⊆{30,31} -> vmcnt(4)
    if (t < NT-2) { WAITVM(12); } else { WAITVM(4); }
    TILE_BODY(t%5);
    if (t+4 < NT) STG(t+4);
    // gate: tile t+1 complete. outstanding ⊆ {t+1..t+4} -> vmcnt(12);
    // t=28: ⊆{29,30,31} -> vmcnt(8); t=30: ⊆{31} -> vmcnt(0)
    if (t < NT-4)       { WAITVM(12); }
    else if (t == NT-4) { WAITVM(8); }
    else                { WAITVM(0); }
    TILE_BODY((t+1)%5);
    asm volatile("s_waitcnt lgkmcnt(0)" ::: "memory");
    __builtin_amdgcn_sched_barrier(0);
    BAR();
  }
#undef STG
#undef TILE_BODY

  // ---- epilogue (r9-r11 verified): LDS-staged coalesced C writes (512B row-runs)
  {
    u16* reg = &L[w*8192];
    #pragma unroll
    for (int nf=0; nf<4; ++nf){
      int col = nf*16 + lr;
      float bv = bias[n0 + wn*64 + col];
      #pragma unroll
      for (int mi=0; mi<8; ++mi){
        #pragma unroll
        for (int r=0;r<4;r++){
          int rr = mi*16 + lk*4 + r;
          reg[rr*64 + (col ^ ((rr&7)<<3))] = f2bu(acc[mi][nf][r] + bv);
        }
      }
    }
    asm volatile("s_waitcnt lgkmcnt(0)" ::: "memory");
    BAR();
    int co = (tid&31)*8;
    int rgn_c = co>>6;
    int c6 = co&63;
    #pragma unroll
    for (int p=0; p<16; ++p){
      int rI = p*16 + (tid>>5);
      int wreg = ((rI>>7)<<2) + rgn_c;
      int rr = rI & 127;
      const u16* src = &L[wreg*8192 + rr*64 + (c6 ^ ((rr&7)<<3))];
      uint4 v = *(const uint4*)src;
      *(uint4*)&Q[(size_t)(m0+rI)*N + n0 + co] = v;
    }
  }
}

// ---------------- per-token head-attention (bf16 qkv input; r4/r7/r9 verified) ----------------
__device__ inline void load16fb(const u16* p, float* f){
  uint4 a = ((const uint4*)p)[0], b4 = ((const uint4*)p)[1];
  f[0]=bl(a.x);  f[1]=bh(a.x);  f[2]=bl(a.y);  f[3]=bh(a.y);
  f[4]=bl(a.z);  f[5]=bh(a.z);  f[6]=bl(a.w);  f[7]=bh(a.w);
  f[8]=bl(b4.x); f[9]=bh(b4.x); f[10]=bl(b4.y);f[11]=bh(b4.y);
  f[12]=bl(b4.z);f[13]=bh(b4.z);f[14]=bl(b4.w);f[15]=bh(b4.w);
}

// 1 wave per token; lane = h*4 + dq; dq owns d in [dq*16, dq*16+16).
__global__ __launch_bounds__(256) void k_attn(const u16* __restrict__ Qkv,
                                              float* __restrict__ out){
  __shared__ __align__(16) u16 sm[4][3072];
  int w = threadIdx.x>>6, lane = threadIdx.x&63;
  int token = blockIdx.x*4 + w;
  const uint4* src = (const uint4*)(Qkv + (size_t)token*3072);
  uint4* dst = (uint4*)&sm[w][0];
  for (int i = lane; i < 384; i += 64) dst[i] = src[i];
  __syncthreads();

  int h = lane>>2, dq = lane&3;
  const u16* base = &sm[w][0];
  float qf[16];
  load16fb(base + h*192 + dq*16, qf);

  const float scale = 0.07216878364870323f;  // 1/sqrt(192)
  float s[16];
  #pragma unroll
  for (int g=0; g<16; ++g){
    float kf[16];
    load16fb(base + g*192 + 64 + dq*16, kf);
    float a = 0.f;
    #pragma unroll
    for (int j=0;j<16;j++) a += qf[j]*kf[j];
    a += __shfl_xor(a, 1);
    a += __shfl_xor(a, 2);
    s[g] = a * scale;
  }
  float mx = s[0];
  #pragma unroll
  for (int g=1; g<16; ++g) mx = fmaxf(mx, s[g]);
  float sum = 0.f;
  #pragma unroll
  for (int g=0; g<16; ++g){ s[g] = __expf(s[g]-mx); sum += s[g]; }
  float inv = 1.f/sum;

  float o[16];
  #pragma unroll
  for (int j=0;j<16;j++) o[j] = 0.f;
  #pragma unroll
  for (int g=0; g<16; ++g){
    float wg = s[g]*inv;
    float vf[16];
    load16fb(base + g*192 + 128 + dq*16, vf);
    #pragma unroll
    for (int j=0;j<16;j++) o[j] += wg*vf[j];
  }
  float* op = out + (size_t)token*1024 + h*64 + dq*16;
  #pragma unroll
  for (int i=0;i<4;i++)
    ((float4*)op)[i] = make_float4(o[i*4], o[i*4+1], o[i*4+2], o[i*4+3]);
}

// ---------------- fallback (ws too small): fully fused, f32 VALU, slow but correct ----------------
__global__ __launch_bounds__(256) void k_fallback(const float* __restrict__ X,
                                                  const float* __restrict__ W,
                                                  const float* __restrict__ bias,
                                                  float* __restrict__ out){
  int token = blockIdx.x;
  __shared__ float xs[1024];
  __shared__ float qkvs[3072];
  __shared__ float ss[16][16];
  __shared__ float ww[16][16];
  for (int i=threadIdx.x; i<1024; i+=256) xs[i] = X[(size_t)token*1024 + i];
  __syncthreads();
  for (int n=threadIdx.x; n<3072; n+=256){
    float acc = bias[n];
    for (int k=0;k<1024;k++) acc += xs[k]*W[(size_t)k*3072 + n];
    qkvs[n] = acc;
  }
  __syncthreads();
  {
    int t = threadIdx.x, h = t>>4, g = t&15;
    float a = 0.f;
    for (int d=0; d<64; d++) a += qkvs[h*192 + d]*qkvs[g*192 + 64 + d];
    ss[h][g] = a * 0.07216878364870323f;
  }
  __syncthreads();
  if (threadIdx.x < 16){
    int hh = threadIdx.x;
    float m = -1e30f;
    for (int g=0;g<16;g++) m = fmaxf(m, ss[hh][g]);
    float sum = 0.f;
    for (int g=0;g<16;g++){ float e = __expf(ss[hh][g]-m); ww[hh][g]=e; sum+=e; }
    float inv = 1.f/sum;
    for (int g=0;g<16;g++) ww[hh][g] *= inv;
  }
  __syncthreads();
  for (int i=threadIdx.x; i<1024; i+=256){
    int h = i>>6, d = i&63;
    float a = 0.f;
    for (int g=0;g<16;g++) a += ww[h][g]*qkvs[g*192 + 128 + d];
    out[(size_t)token*1024 + i] = a;
  }
}

extern "C" void kernel_launch(void* const* d_in, const int* in_sizes, int n_in,
                              void* d_out, int out_size, void* d_ws, size_t ws_size,
                              hipStream_t stream){
  const float* x    = (const float*)d_in[0];   // [4,4096,1024] f32
  const float* wk   = (const float*)d_in[1];   // [1024,16,192] f32
  const float* bias = (const float*)d_in[2];   // [16,192] f32
  float* out = (float*)d_out;                  // [4,4096,16,64] f32

  const size_t offW = 33554432;                       // Xb: 16M bf16
  const size_t offQ = offW + 6291456;                 // Wt: 3M bf16
  const size_t need = offQ + (size_t)16384*3072*2;    // Q bf16

  if (ws_size >= need){
    u16* Xb = (u16*)d_ws;
    u16* Wt = (u16*)((char*)d_ws + offW);
    u16* Q  = (u16*)((char*)d_ws + offQ);
    k_conv  <<<5120, 256, 0, stream>>>(x, Xb, wk, Wt);
    k_gemm2 <<<768, 512, 0, stream>>>(Xb, Wt, bias, Q);
    k_attn  <<<4096, 256, 0, stream>>>(Q, out);
  } else {
    k_fallback<<<16384, 256, 0, stream>>>(x, wk, bias, out);
  }
}